// Round 4
// baseline (196.188 us; speedup 1.0000x reference)
//
#include <hip/hip_runtime.h>
#include <stdint.h>

// Problem constants (fixed by setup_inputs: B=2,H=16,N=2048,D=128), f32 in/out.
#define NN 2048
#define DD 128
#define BHH 32
#define QT 64   // queries per block (32 per wave x 2 waves)
#define KT 64   // keys per K/V tile

typedef short v8s __attribute__((ext_vector_type(8)));   // 8 bf16 (raw bits)
typedef short v4s __attribute__((ext_vector_type(4)));   // 4 bf16
typedef float v4f __attribute__((ext_vector_type(4)));
typedef float v16f __attribute__((ext_vector_type(16)));
typedef unsigned int u32;
typedef u32 u32x2 __attribute__((ext_vector_type(2)));
typedef u32 u32x4 __attribute__((ext_vector_type(4)));

__device__ __forceinline__ unsigned short f2bf(float x) {
  unsigned u = __builtin_bit_cast(unsigned, x);
  u += 0x7fffu + ((u >> 16) & 1u);   // RNE
  return (unsigned short)(u >> 16);
}

__device__ __forceinline__ v8s cvt8(const float* __restrict__ p) {
  v8s r;
#pragma unroll
  for (int j = 0; j < 8; j++) r[j] = (short)f2bf(p[j]);
  return r;
}

// v_cvt_pk_bf16_f32: 2 f32 -> packed 2x bf16 (RNE), single VALU op.
__device__ __forceinline__ u32 pk2(float a, float b) {
  u32 r;
  asm("v_cvt_pk_bf16_f32 %0, %1, %2" : "=v"(r) : "v"(a), "v"(b));
  return r;
}

// Fused prep, one dispatch. grid=(32,2,64):
//  z <  32: Vt[bh=z][d][n] = bf16(V[bh][n][d]) via 64x64 LDS tile
//  z >= 32: Kb[bh=z-32] chunk = bf16(K chunk), flat copy, 16 elems/thread
__global__ __launch_bounds__(256) void prep(const float* __restrict__ K, const float* __restrict__ V,
                     unsigned short* __restrict__ Kb, unsigned short* __restrict__ Vt) {
  const int z = blockIdx.z;
  const int tid = threadIdx.x;
  if (z >= BHH) {
    const int bh = z - BHH;
    const int chunk = blockIdx.y * 32 + blockIdx.x;           // 0..63
    size_t base = (size_t)bh * NN * DD + (size_t)chunk * 4096 + (size_t)tid * 16;
    v4f f0 = *(const v4f*)(K + base);
    v4f f1 = *(const v4f*)(K + base + 4);
    v4f f2 = *(const v4f*)(K + base + 8);
    v4f f3 = *(const v4f*)(K + base + 12);
    u32x4 w0 = { pk2(f0[0], f0[1]), pk2(f0[2], f0[3]), pk2(f1[0], f1[1]), pk2(f1[2], f1[3]) };
    u32x4 w1 = { pk2(f2[0], f2[1]), pk2(f2[2], f2[3]), pk2(f3[0], f3[1]), pk2(f3[2], f3[3]) };
    *(u32x4*)(Kb + base) = w0;
    *(u32x4*)(Kb + base + 8) = w1;
    return;
  }
  __shared__ __align__(16) unsigned short t[64 * 68];  // [d][n], stride 68 shorts
  const int bh = z;
  const int n0 = blockIdx.x * 64, d0 = blockIdx.y * 64;
  const int c16 = tid & 15, r4 = tid >> 4;
  const float* src = V + ((size_t)bh * NN + n0 + r4 * 4) * DD + d0 + c16 * 4;
  v4f f0 = *(const v4f*)(src);
  v4f f1 = *(const v4f*)(src + DD);
  v4f f2 = *(const v4f*)(src + 2 * DD);
  v4f f3 = *(const v4f*)(src + 3 * DD);
#pragma unroll
  for (int j = 0; j < 4; j++) {
    u32x2 w = { pk2(f0[j], f1[j]), pk2(f2[j], f3[j]) };   // n-order r4*4..+3
    *(u32x2*)(t + (c16 * 4 + j) * 68 + r4 * 4) = w;
  }
  __syncthreads();
  unsigned short* dst = Vt + ((size_t)bh * DD + d0) * NN + n0;
#pragma unroll
  for (int p = 0; p < 2; p++) {
    int d = p * 32 + (tid >> 3);
    int nc = (tid & 7) * 8;
    v4s x0 = *(const v4s*)(t + d * 68 + nc);
    v4s x1 = *(const v4s*)(t + d * 68 + nc + 4);
    v8s o = { x0[0], x0[1], x0[2], x0[3], x1[0], x1[1], x1[2], x1[3] };
    *(v8s*)(dst + (size_t)d * NN + nc) = o;
  }
}

// Flash-style sink+sliding-window attention, f32 in/out, bf16 MFMA compute.
// R4: LDS-BW was the r3 bottleneck (each 16q-wave read whole 32KB K+V tile:
// ~170KB LDS/tile-unit ~= 42us of the 80us). Now: 2 waves x 32 queries with
// mfma_f32_32x32x16_bf16 -> per-unit LDS = 2x32KB reads + 32KB writes = 96KB.
// P never touches LDS: swapped QK^T gives S^T (col=q=lane&31,
// row=key=(reg&3)+8*(reg>>2)+4*(lane>>5)); cvt_pk + permlane32_swap converts
// C-layout -> PV A-frags ({w0,w2}=swap(pk(s0,s1),pk(s4,s5)),
// {w1,w3}=swap(pk(s2,s3),pk(s6,s7)); +8 regs for kt1) fully in registers.
// LDS fragment-major: frag = contiguous 1KB, read/write at frag*512+l*8
// shorts (conflict-free b128 both sides).
// Pipeline (r3-proven): tile t+1 global loads -> regs issue right after tile
// t's post-write barrier; consumed next iteration.
// Jobs (r3-verified): 24 jobs/bh x 17 tile-units, contiguous tile ranges,
// sink16 fast tile for heavy jobs. 768 blocks x 128 thr, 3 blocks/CU.
// mfma_f32_32x32x16_bf16 layouts: A: lane holds A[m=lane&31][k=(lane>>5)*8+j]
// B: B[k=(lane>>5)*8+j][n=lane&31]; C/D: D[row=(reg&3)+8*(reg>>2)+4*(lane>>5)]
// [col=lane&31]  (m74/m101-verified mapping).
template <bool PREPPED>
__global__ __launch_bounds__(128, 2) void attn(
    const float* __restrict__ Q,
    const float* __restrict__ Kf, const unsigned short* __restrict__ Kb,
    const unsigned short* __restrict__ Vt, const float* __restrict__ Vf,
    const int* __restrict__ nsp, const int* __restrict__ wsp,
    float* __restrict__ O) {
  const int ns = nsp[0], win = wsp[0];
  const int x = blockIdx.x;              // 0..767
  const int xcd = x & 7, slot = x >> 3;  // slot 0..95
  const int bh = xcd + 8 * (slot / 24);
  const int jobid = slot % 24;           // 0..23
  int qis[2], njobs;
  if (jobid < 16) { njobs = 1; qis[0] = 31 - jobid; qis[1] = 0; }
  else { int p = jobid - 16; njobs = 2; qis[0] = 15 - p; qis[1] = p; }

  const int tid = threadIdx.x;
  const int w = tid >> 6;      // wave 0..1
  const int l = tid & 63;
  const int m = l & 31;        // q-col within wave's 32 queries; also key-row for A
  const int hi = l >> 5;       // half-wave
  const int rbase = 4 * hi;    // C/D row offset

  __shared__ __align__(16) unsigned short Kl[16 * 512];  // 16 frags x 1KB
  __shared__ __align__(16) unsigned short Vl[16 * 512];  // 16 frags x 1KB

  const float csc = 0.088388347648318447f * 1.4426950408889634f;  // 1/sqrt(128)*log2(e)

  // staging bases
  const size_t kK = ((size_t)bh * NN + w * 32 + m) * DD + hi * 8;      // + kb*DD + i*16
  const unsigned short* vtb = Vt + (size_t)bh * DD * NN;

  // P C-layout -> PV A-frag via cvt_pk + permlane32_swap (all-register)
  auto mkpa = [&](float a0, float a1, float a2, float a3,
                  float b0, float b1, float b2, float b3) -> v8s {
    u32x2 r02 = __builtin_amdgcn_permlane32_swap(pk2(a0, a1), pk2(b0, b1), false, false);
    u32x2 r13 = __builtin_amdgcn_permlane32_swap(pk2(a2, a3), pk2(b2, b3), false, false);
    u32x4 pw = { r02[0], r13[0], r02[1], r13[1] };
    return __builtin_bit_cast(v8s, pw);
  };

  for (int ji = 0; ji < njobs; ji++) {
    const int q0 = qis[ji] * QT;
    const int qrow0w = q0 + w * 32;   // this wave's 32 query rows
    const int qi = qrow0w + m;        // this lane's query (S^T col)

    // Q B-frags, pre-scaled: lane holds Q[qi][kc*16 + hi*8 + j]*csc
    v8s qf[8];
    {
      const float* qb = Q + ((size_t)bh * NN + qi) * DD + hi * 8;
#pragma unroll
      for (int kc = 0; kc < 8; kc++) {
        v8s r;
#pragma unroll
        for (int e = 0; e < 8; e++) r[e] = (short)f2bf(qb[kc * 16 + e] * csc);
        qf[kc] = r;
      }
    }

    float lsum = 0.f;
    v16f oa[4];
#pragma unroll
    for (int nc = 0; nc < 4; nc++) oa[nc] = (v16f)(0.f);

    // ---- tile range (contiguous, r3-verified) ----
    const int wstart = q0 - win + 1;
    const bool sink16 = (wstart > KT - 1) && (ns <= 16);
    const int kb_lo = sink16 ? ((wstart >> 6) << 6) : 0;
    const int kb_hi = q0 + QT;

    // register prefetch: wave w stages K frags w*8+i (ct=w, kc=i) and
    // V frags w*8+i (kt=w*2+(i>>2), nc=i&3)
    v8s kst[8], vst[8];
    auto stage_load = [&](int kb) {
#pragma unroll
      for (int i = 0; i < 8; i++) {
        if constexpr (PREPPED) {
          kst[i] = *(const v8s*)(Kb + kK + (size_t)kb * DD + i * 16);
        } else {
          kst[i] = cvt8(Kf + kK + (size_t)kb * DD + i * 16);
        }
      }
#pragma unroll
      for (int i = 0; i < 8; i++) {
        const int kt = w * 2 + (i >> 2), nc = i & 3;
        if constexpr (PREPPED) {
          vst[i] = *(const v8s*)(vtb + ((size_t)nc * 32 + m) * NN + kb + kt * 16 + hi * 8);
        } else {
          v8s r;
#pragma unroll
          for (int e = 0; e < 8; e++)
            r[e] = (short)f2bf(Vf[((size_t)bh * NN + kb + kt * 16 + hi * 8 + e) * DD + nc * 32 + m]);
          vst[i] = r;
        }
      }
    };

    stage_load(kb_lo);  // in flight during sink compute / first barrier

    if (sink16) {
      // sink tile: keys 0..31 in one 32x32 block (keys >= ns masked)
      v8s kf0[8];
      const size_t g0 = ((size_t)bh * NN + m) * DD + hi * 8;
#pragma unroll
      for (int kc = 0; kc < 8; kc++)
        kf0[kc] = PREPPED ? *(const v8s*)(Kb + g0 + kc * 16) : cvt8(Kf + g0 + kc * 16);
      v16f s = (v16f)(0.f);
#pragma unroll
      for (int kc = 0; kc < 8; kc++)
        s = __builtin_amdgcn_mfma_f32_32x32x16_bf16(kf0[kc], qf[kc], s, 0, 0, 0);
#pragma unroll
      for (int reg = 0; reg < 16; reg++) {
        const int kj = (reg & 3) + 8 * (reg >> 2) + rbase;
        const bool valid = (kj < ns) && (kj <= qi);
        s[reg] = valid ? __builtin_amdgcn_exp2f(s[reg]) : 0.f;
        lsum += s[reg];
      }
      // keys 16..31 all masked (ns<=16): only kt0 PV needed
      v8s pa = mkpa(s[0], s[1], s[2], s[3], s[4], s[5], s[6], s[7]);
#pragma unroll
      for (int nc = 0; nc < 4; nc++) {
        v8s vf;
        if constexpr (PREPPED) {
          vf = *(const v8s*)(vtb + ((size_t)nc * 32 + m) * NN + hi * 8);
        } else {
#pragma unroll
          for (int e = 0; e < 8; e++)
            vf[e] = (short)f2bf(Vf[((size_t)bh * NN + hi * 8 + e) * DD + nc * 32 + m]);
        }
        oa[nc] = __builtin_amdgcn_mfma_f32_32x32x16_bf16(pa, vf, oa[nc], 0, 0, 0);
      }
    }

    // ---- pipelined main loop ----
    for (int kb = kb_lo; kb < kb_hi; kb += KT) {
      __syncthreads();  // previous tile's LDS reads complete
#pragma unroll
      for (int i = 0; i < 8; i++)
        *(v8s*)(Kl + (w * 8 + i) * 512 + l * 8) = kst[i];
#pragma unroll
      for (int i = 0; i < 8; i++)
        *(v8s*)(Vl + (w * 8 + i) * 512 + l * 8) = vst[i];
      __syncthreads();  // staging visible
      if (kb + KT < kb_hi) stage_load(kb + KT);  // hides under compute

#pragma unroll
      for (int ct = 0; ct < 2; ct++) {
        // S^T(32x32) = K[kb+ct*32..][.] x Q^T : lane holds col q=qi,
        // rows key = kb+ct*32 + (reg&3)+8*(reg>>2)+rbase
        v16f s = (v16f)(0.f);
        __builtin_amdgcn_s_setprio(1);
#pragma unroll
        for (int kc = 0; kc < 8; kc++) {
          v8s kfr = *(const v8s*)(Kl + (ct * 8 + kc) * 512 + l * 8);
          s = __builtin_amdgcn_mfma_f32_32x32x16_bf16(kfr, qf[kc], s, 0, 0, 0);
        }
        __builtin_amdgcn_s_setprio(0);

        const int kbct = kb + ct * 32;
        const bool full = (kbct + 31 <= qrow0w) && (kbct >= qrow0w + 32 - win);
        if (full) {
#pragma unroll
          for (int reg = 0; reg < 16; reg++) {
            s[reg] = __builtin_amdgcn_exp2f(s[reg]);
            lsum += s[reg];
          }
        } else {
#pragma unroll
          for (int reg = 0; reg < 16; reg++) {
            const int kj = kbct + (reg & 3) + 8 * (reg >> 2) + rbase;
            const bool valid = (kj <= qi) && ((kj < ns) || (qi - kj < win));
            s[reg] = valid ? __builtin_amdgcn_exp2f(s[reg]) : 0.f;
            lsum += s[reg];
          }
        }

        // P -> A-frags in registers (no LDS)
        v8s pa0 = mkpa(s[0], s[1], s[2], s[3], s[4], s[5], s[6], s[7]);
        v8s pa1 = mkpa(s[8], s[9], s[10], s[11], s[12], s[13], s[14], s[15]);

        __builtin_amdgcn_s_setprio(1);
#pragma unroll
        for (int ktl = 0; ktl < 2; ktl++) {
          const v8s pf = ktl ? pa1 : pa0;
          const int kt = ct * 2 + ktl;
#pragma unroll
          for (int nc = 0; nc < 4; nc++) {
            v8s vfr = *(const v8s*)(Vl + (kt * 4 + nc) * 512 + l * 8);
            oa[nc] = __builtin_amdgcn_mfma_f32_32x32x16_bf16(pf, vfr, oa[nc], 0, 0, 0);
          }
        }
        __builtin_amdgcn_s_setprio(0);
      }
    }

    // epilogue: lane holds lsum partial for q=qi over its key-half; combine
    float lt = lsum + __shfl_xor(lsum, 32, 64);
    const float inv = 1.f / lt;
    float* ob = O + ((size_t)bh * NN + qrow0w) * DD;
#pragma unroll
    for (int reg = 0; reg < 16; reg++) {
      const int row = (reg & 3) + 8 * (reg >> 2) + rbase;
      const float iv = __shfl(inv, row, 64);   // lane 'row' holds q=qrow0w+row
#pragma unroll
      for (int nc = 0; nc < 4; nc++)
        ob[(size_t)row * DD + nc * 32 + m] = oa[nc][reg] * iv;
    }
  }
}

extern "C" void kernel_launch(void* const* d_in, const int* in_sizes, int n_in,
                              void* d_out, int out_size, void* d_ws, size_t ws_size,
                              hipStream_t stream) {
  const float* q = (const float*)d_in[0];
  const float* k = (const float*)d_in[1];
  const float* v = (const float*)d_in[2];
  const int* nsp = (const int*)d_in[3];
  const int* wsp = (const int*)d_in[4];
  float* out = (float*)d_out;

  const size_t half = (size_t)BHH * NN * DD * sizeof(unsigned short);  // 16 MiB
  const int nblocks = BHH * 24;  // uniform 17-unit jobs

  if (ws_size >= 2 * half) {
    unsigned short* kbf = (unsigned short*)d_ws;
    unsigned short* vt = (unsigned short*)((char*)d_ws + half);
    prep<<<dim3(32, 2, 2 * BHH), 256, 0, stream>>>(k, v, kbf, vt);
    attn<true><<<nblocks, 128, 0, stream>>>(q, k, kbf, vt, v, nsp, wsp, out);
  } else {
    attn<false><<<nblocks, 128, 0, stream>>>(q, k, nullptr, nullptr, v, nsp, wsp, out);
  }
}